// Round 1
// baseline (109.728 us; speedup 1.0000x reference)
//
#include <hip/hip_runtime.h>

#define S_DIM 64
#define B_DIM 256
#define D_DIM 1024
#define BS (B_DIM * S_DIM)        /* 16384 */
#define LP (B_DIM * (S_DIM - 1)) /* 16128 */

__device__ __forceinline__ float wave_red(float v) {
#pragma unroll
  for (int o = 32; o > 0; o >>= 1) v += __shfl_down(v, o, 64);
  return v;
}

// ---------------------------------------------------------------------------
// Kernel 1: per-row reductions.
// Grid: B_DIM * 4 blocks; block handles rows s in [chunk*16, chunk*16+16) of
// batch b, carrying the previous row in registers for the adjacent dots.
// ws layout (floats): nl2[BS] | nt2[BS] | lt[BS] | ajl[BS] | ajt[BS] | dcl[LP] | dct[LP]
// ---------------------------------------------------------------------------
__global__ __launch_bounds__(256) void row_stats_kernel(
    const float* __restrict__ logits, const float* __restrict__ tgt,
    float* __restrict__ ws) {
  const int blk = blockIdx.x;
  const int b = blk >> 2;
  const int s0 = (blk & 3) << 4;
  const int tid = threadIdx.x;
  const int wid = tid >> 6;
  const int lane = tid & 63;

  float* nl2 = ws;
  float* nt2 = ws + BS;
  float* lt  = ws + 2 * BS;
  float* ajl = ws + 3 * BS;
  float* ajt = ws + 4 * BS;

  __shared__ float red[2][20];

  float4 pl = make_float4(0.f, 0.f, 0.f, 0.f);
  float4 pt = pl;
  if (s0 > 0) {
    size_t off = ((size_t)(s0 - 1) * B_DIM + b) * D_DIM;
    pl = reinterpret_cast<const float4*>(logits + off)[tid];
    pt = reinterpret_cast<const float4*>(tgt + off)[tid];
  }
#pragma unroll 1
  for (int s = s0; s < s0 + 16; ++s) {
    size_t off = ((size_t)s * B_DIM + b) * D_DIM;
    float4 cl = reinterpret_cast<const float4*>(logits + off)[tid];
    float4 ct = reinterpret_cast<const float4*>(tgt + off)[tid];
    float v0 = cl.x * cl.x + cl.y * cl.y + cl.z * cl.z + cl.w * cl.w;
    float v1 = ct.x * ct.x + ct.y * ct.y + ct.z * ct.z + ct.w * ct.w;
    float v2 = cl.x * ct.x + cl.y * ct.y + cl.z * ct.z + cl.w * ct.w;
    float v3 = cl.x * pl.x + cl.y * pl.y + cl.z * pl.z + cl.w * pl.w;
    float v4 = ct.x * pt.x + ct.y * pt.y + ct.z * pt.z + ct.w * pt.w;
    v0 = wave_red(v0); v1 = wave_red(v1); v2 = wave_red(v2);
    v3 = wave_red(v3); v4 = wave_red(v4);
    const int buf = s & 1;
    if (lane == 0) {
      float* r = &red[buf][wid * 5];
      r[0] = v0; r[1] = v1; r[2] = v2; r[3] = v3; r[4] = v4;
    }
    __syncthreads();
    if (tid < 5) {
      const float* rb = red[buf];
      float r = rb[tid] + rb[5 + tid] + rb[10 + tid] + rb[15 + tid];
      int i = b * S_DIM + s;
      if      (tid == 0) nl2[i] = r;
      else if (tid == 1) nt2[i] = r;
      else if (tid == 2) lt[i]  = r;
      else if (tid == 3) { if (s > 0) ajl[i - 1] = r; }
      else               { if (s > 0) ajt[i - 1] = r; }
    }
    pl = cl; pt = ct;
  }
}

// ---------------------------------------------------------------------------
// Kernel 2: finalize — one block of 1024 threads.
// ---------------------------------------------------------------------------
__device__ __forceinline__ float block_red(float v, float* sm, int tid) {
  __syncthreads();
  v = wave_red(v);
  if ((tid & 63) == 0) sm[tid >> 6] = v;
  __syncthreads();
  float r = 0.f;
  if (tid < 16) r = sm[tid];
  r = wave_red(r);
  return r;  // valid at tid 0
}

__global__ __launch_bounds__(1024) void finalize_kernel(
    const unsigned char* __restrict__ mask, float* __restrict__ ws,
    float* __restrict__ out) {
  const float* nl2 = ws;
  const float* nt2 = ws + BS;
  const float* lt  = ws + 2 * BS;
  const float* ajl = ws + 3 * BS;
  const float* ajt = ws + 4 * BS;
  float* dcl = ws + 5 * BS;
  float* dct = dcl + LP;

  __shared__ float sm[16];
  __shared__ int scan_s[1024];
  __shared__ int s_flag;

  const int tid = threadIdx.x;
  if (tid == 0) s_flag = 0;
  __syncthreads();
  // Detect mask element width: byte-per-element vs 4-byte-per-element.
  int any = 0;
  for (int i = tid; i < BS; i += 1024)
    if ((i & 3) == 1 && mask[i]) any = 1;
  if (any) s_flag = 1;
  __syncthreads();
  const bool isbyte = (s_flag != 0);

  // Phase A: valid count, mse sum, cos sum over all (b,s) rows.
  float nv = 0.f, mse = 0.f, coss = 0.f;
  for (int i = tid; i < BS; i += 1024) {
    bool valid = mask[isbyte ? i : (i << 2)] == 0;
    if (valid) {
      float a = nl2[i], q = nt2[i], c = lt[i];
      nv += 1.f;
      mse += a + q - 2.f * c;
      coss += 1.f - c / (fmaxf(sqrtf(a), 1e-8f) * fmaxf(sqrtf(q), 1e-8f));
    }
  }

  // Phase B: per-pair d_l/d_t, delta loss, per-thread valid-pair counts.
  const int base = tid * 16;
  const int lim = (base + 16 < LP) ? (base + 16) : LP;
  int lcnt = 0;
  float dsum = 0.f;
  for (int p = base; p < lim; ++p) {
    int b = p / 63;
    int s = p - b * 63;
    int i0 = b * S_DIM + s;
    bool pv = (mask[isbyte ? i0 : (i0 << 2)] == 0) &&
              (mask[isbyte ? (i0 + 1) : ((i0 + 1) << 2)] == 0);
    if (pv) {
      float dl = ajl[i0] / (fmaxf(sqrtf(nl2[i0]), 1e-6f) *
                            fmaxf(sqrtf(nl2[i0 + 1]), 1e-6f));
      float dt = ajt[i0] / (fmaxf(sqrtf(nt2[i0]), 1e-6f) *
                            fmaxf(sqrtf(nt2[i0 + 1]), 1e-6f));
      float w = dl - dt;
      dsum += w * w;
      ++lcnt;
    }
  }

  // Inclusive Hillis-Steele scan of per-thread counts -> compaction ranks.
  scan_s[tid] = lcnt;
  __syncthreads();
  for (int off = 1; off < 1024; off <<= 1) {
    int v = (tid >= off) ? scan_s[tid - off] : 0;
    __syncthreads();
    scan_s[tid] += v;
    __syncthreads();
  }
  const int cnt = scan_s[1023];
  int rank = scan_s[tid] - lcnt;

  // Second pass: scatter compacted d values.
  for (int p = base; p < lim; ++p) {
    int b = p / 63;
    int s = p - b * 63;
    int i0 = b * S_DIM + s;
    bool pv = (mask[isbyte ? i0 : (i0 << 2)] == 0) &&
              (mask[isbyte ? (i0 + 1) : ((i0 + 1) << 2)] == 0);
    if (pv) {
      float dl = ajl[i0] / (fmaxf(sqrtf(nl2[i0]), 1e-6f) *
                            fmaxf(sqrtf(nl2[i0 + 1]), 1e-6f));
      float dt = ajt[i0] / (fmaxf(sqrtf(nt2[i0]), 1e-6f) *
                            fmaxf(sqrtf(nt2[i0 + 1]), 1e-6f));
      dcl[rank] = dl;
      dct[rank] = dt;
      ++rank;
    }
  }
  __threadfence();
  __syncthreads();

  // Phase C: dd loss over compacted adjacent pairs.
  float ddsum = 0.f;
  for (int i = tid; i < cnt - 1; i += 1024) {
    float a0 = dcl[i], a1 = dcl[i + 1];
    float b0 = dct[i], b1 = dct[i + 1];
    float ddl = (a1 - a0) / ((a0 != 0.f) ? a0 : 1e-6f);
    float ddt = (b1 - b0) / ((b0 != 0.f) ? b0 : 1e-6f);
    float w = ddl - ddt;
    ddsum += w * w;
  }

  float r_nv  = block_red(nv,    sm, tid);
  float r_mse = block_red(mse,   sm, tid);
  float r_cos = block_red(coss,  sm, tid);
  float r_del = block_red(dsum,  sm, tid);
  float r_dd  = block_red(ddsum, sm, tid);

  if (tid == 0) {
    float loss = r_mse / (r_nv * (float)D_DIM)
               + r_cos / r_nv
               + r_del / fmaxf((float)cnt, 1.f)
               + (r_dd / fmaxf((float)(cnt - 1), 1.f)) * 0.01f;
    out[0] = loss;
  }
}

extern "C" void kernel_launch(void* const* d_in, const int* in_sizes, int n_in,
                              void* d_out, int out_size, void* d_ws, size_t ws_size,
                              hipStream_t stream) {
  const float* logits = (const float*)d_in[0];
  const float* tgt    = (const float*)d_in[1];
  const unsigned char* mask = (const unsigned char*)d_in[2];
  float* out = (float*)d_out;
  float* ws  = (float*)d_ws;

  row_stats_kernel<<<dim3(B_DIM * 4), dim3(256), 0, stream>>>(logits, tgt, ws);
  finalize_kernel<<<dim3(1), dim3(1024), 0, stream>>>(mask, ws, out);
}

// Round 3
// 65.108 us; speedup vs baseline: 1.6853x; 1.6853x over previous
//
#include <hip/hip_runtime.h>

#define S_DIM 64
#define B_DIM 256
#define D_DIM 1024
#define BS (B_DIM * S_DIM)        /* 16384 */
#define LP (B_DIM * (S_DIM - 1)) /* 16128 */
#define NB2 256                   /* blocks in pair_kernel */

__device__ __forceinline__ float wave_red(float v) {
#pragma unroll
  for (int o = 32; o > 0; o >>= 1) v += __shfl_down(v, o, 64);
  return v;
}

// ---------------------------------------------------------------------------
// Kernel 1: per-row reductions over D.
// ws layout (floats): nl2[BS] | nt2[BS] | lt[BS] | ajl[BS] | ajt[BS] | partial[6*NB2]
// ---------------------------------------------------------------------------
__global__ __launch_bounds__(256) void row_stats_kernel(
    const float* __restrict__ logits, const float* __restrict__ tgt,
    float* __restrict__ ws) {
  const int blk = blockIdx.x;
  const int b = blk >> 2;
  const int s0 = (blk & 3) << 4;
  const int tid = threadIdx.x;
  const int wid = tid >> 6;
  const int lane = tid & 63;

  float* nl2 = ws;
  float* nt2 = ws + BS;
  float* lt  = ws + 2 * BS;
  float* ajl = ws + 3 * BS;
  float* ajt = ws + 4 * BS;

  __shared__ float red[2][20];

  float4 pl = make_float4(0.f, 0.f, 0.f, 0.f);
  float4 pt = pl;
  if (s0 > 0) {
    size_t off = ((size_t)(s0 - 1) * B_DIM + b) * D_DIM;
    pl = reinterpret_cast<const float4*>(logits + off)[tid];
    pt = reinterpret_cast<const float4*>(tgt + off)[tid];
  }
#pragma unroll 1
  for (int s = s0; s < s0 + 16; ++s) {
    size_t off = ((size_t)s * B_DIM + b) * D_DIM;
    float4 cl = reinterpret_cast<const float4*>(logits + off)[tid];
    float4 ct = reinterpret_cast<const float4*>(tgt + off)[tid];
    float v0 = cl.x * cl.x + cl.y * cl.y + cl.z * cl.z + cl.w * cl.w;
    float v1 = ct.x * ct.x + ct.y * ct.y + ct.z * ct.z + ct.w * ct.w;
    float v2 = cl.x * ct.x + cl.y * ct.y + cl.z * ct.z + cl.w * ct.w;
    float v3 = cl.x * pl.x + cl.y * pl.y + cl.z * pl.z + cl.w * pl.w;
    float v4 = ct.x * pt.x + ct.y * pt.y + ct.z * pt.z + ct.w * pt.w;
    v0 = wave_red(v0); v1 = wave_red(v1); v2 = wave_red(v2);
    v3 = wave_red(v3); v4 = wave_red(v4);
    const int buf = s & 1;
    if (lane == 0) {
      float* r = &red[buf][wid * 5];
      r[0] = v0; r[1] = v1; r[2] = v2; r[3] = v3; r[4] = v4;
    }
    __syncthreads();
    if (tid < 5) {
      const float* rb = red[buf];
      float r = rb[tid] + rb[5 + tid] + rb[10 + tid] + rb[15 + tid];
      int i = b * S_DIM + s;
      if      (tid == 0) nl2[i] = r;
      else if (tid == 1) nt2[i] = r;
      else if (tid == 2) lt[i]  = r;
      else if (tid == 3) { if (s > 0) ajl[i - 1] = r; }
      else               { if (s > 0) ajt[i - 1] = r; }
    }
    pl = cl; pt = ct;
  }
}

// ---------------------------------------------------------------------------
// Kernel 2: per-row mask sums + per-pair delta/dd terms. 256 blocks x 64 thr,
// one row and one pair per thread; dd handled by next-valid-pair search.
// ---------------------------------------------------------------------------
__global__ __launch_bounds__(64) void pair_kernel(
    const unsigned char* __restrict__ mask, float* __restrict__ ws) {
  const float* nl2 = ws;
  const float* nt2 = ws + BS;
  const float* lt  = ws + 2 * BS;
  const float* ajl = ws + 3 * BS;
  const float* ajt = ws + 4 * BS;
  float* partial = ws + 5 * BS;

  __shared__ int s_flag;
  const int tid = threadIdx.x;
  if (tid == 0) s_flag = 0;
  __syncthreads();
  // Detect mask element width (byte vs 4-byte). For 4-byte storage, bytes at
  // index 1 mod 4 are always 0; for random byte masks some are 1.
  int any = 0;
  for (int i = tid; i < 4096; i += 64)
    if ((i & 3) == 1 && mask[i]) any = 1;
  if (any) s_flag = 1;
  __syncthreads();
  const bool isbyte = (s_flag != 0);

  const int gid = blockIdx.x * 64 + tid;

  float nv = 0.f, mse = 0.f, coss = 0.f, dsum = 0.f, ddsum = 0.f, cntf = 0.f;

  // Row terms.
  if (mask[isbyte ? gid : (gid << 2)] == 0) {
    float a = nl2[gid], q = nt2[gid], c = lt[gid];
    nv = 1.f;
    mse = a + q - 2.f * c;
    coss = 1.f - c / (fmaxf(sqrtf(a), 1e-8f) * fmaxf(sqrtf(q), 1e-8f));
  }

  // Pair terms.
  if (gid < LP) {
    const int b = gid / 63;
    const int s = gid - b * 63;
    const int i0 = b * S_DIM + s;
    bool pv = (mask[isbyte ? i0 : (i0 << 2)] == 0) &&
              (mask[isbyte ? (i0 + 1) : ((i0 + 1) << 2)] == 0);
    if (pv) {
      float dl = ajl[i0] / (fmaxf(sqrtf(nl2[i0]), 1e-6f) *
                            fmaxf(sqrtf(nl2[i0 + 1]), 1e-6f));
      float dt = ajt[i0] / (fmaxf(sqrtf(nt2[i0]), 1e-6f) *
                            fmaxf(sqrtf(nt2[i0 + 1]), 1e-6f));
      float w = dl - dt;
      dsum = w * w;
      cntf = 1.f;
      // Find the next valid pair in flattened order -> dd term.
      for (int p = gid + 1; p < LP; ++p) {
        int bq = p / 63;
        int sq = p - bq * 63;
        int j0 = bq * S_DIM + sq;
        bool qv = (mask[isbyte ? j0 : (j0 << 2)] == 0) &&
                  (mask[isbyte ? (j0 + 1) : ((j0 + 1) << 2)] == 0);
        if (qv) {
          float dlq = ajl[j0] / (fmaxf(sqrtf(nl2[j0]), 1e-6f) *
                                 fmaxf(sqrtf(nl2[j0 + 1]), 1e-6f));
          float dtq = ajt[j0] / (fmaxf(sqrtf(nt2[j0]), 1e-6f) *
                                 fmaxf(sqrtf(nt2[j0 + 1]), 1e-6f));
          float ddl = (dlq - dl) / ((dl != 0.f) ? dl : 1e-6f);
          float ddt = (dtq - dt) / ((dt != 0.f) ? dt : 1e-6f);
          float u = ddl - ddt;
          ddsum = u * u;
          break;
        }
      }
    }
  }

  nv = wave_red(nv); mse = wave_red(mse); coss = wave_red(coss);
  dsum = wave_red(dsum); ddsum = wave_red(ddsum); cntf = wave_red(cntf);
  if (tid == 0) {
    partial[0 * NB2 + blockIdx.x] = nv;
    partial[1 * NB2 + blockIdx.x] = mse;
    partial[2 * NB2 + blockIdx.x] = coss;
    partial[3 * NB2 + blockIdx.x] = dsum;
    partial[4 * NB2 + blockIdx.x] = ddsum;
    partial[5 * NB2 + blockIdx.x] = cntf;
  }
}

// ---------------------------------------------------------------------------
// Kernel 3: combine the 256 partials into the scalar loss.
// ---------------------------------------------------------------------------
__global__ __launch_bounds__(256) void final_combine_kernel(
    const float* __restrict__ ws, float* __restrict__ out) {
  const float* partial = ws + 5 * BS;
  __shared__ float sm[4];
  const int tid = threadIdx.x;
  float acc[6];
#pragma unroll
  for (int k = 0; k < 6; ++k) {
    float v = partial[k * NB2 + tid];
    v = wave_red(v);
    __syncthreads();
    if ((tid & 63) == 0) sm[tid >> 6] = v;
    __syncthreads();
    float r = 0.f;
    if (tid < 4) r = sm[tid];
    r = wave_red(r);
    acc[k] = r;
  }
  if (tid == 0) {
    float nv = acc[0], mse = acc[1], coss = acc[2];
    float dsum = acc[3], ddsum = acc[4], cnt = acc[5];
    float loss = mse / (nv * (float)D_DIM)
               + coss / nv
               + dsum / fmaxf(cnt, 1.f)
               + (ddsum / fmaxf(cnt - 1.f, 1.f)) * 0.01f;
    out[0] = loss;
  }
}

extern "C" void kernel_launch(void* const* d_in, const int* in_sizes, int n_in,
                              void* d_out, int out_size, void* d_ws, size_t ws_size,
                              hipStream_t stream) {
  const float* logits = (const float*)d_in[0];
  const float* tgt    = (const float*)d_in[1];
  const unsigned char* mask = (const unsigned char*)d_in[2];
  float* out = (float*)d_out;
  float* ws  = (float*)d_ws;

  row_stats_kernel<<<dim3(B_DIM * 4), dim3(256), 0, stream>>>(logits, tgt, ws);
  pair_kernel<<<dim3(NB2), dim3(64), 0, stream>>>(mask, ws);
  final_combine_kernel<<<dim3(1), dim3(256), 0, stream>>>(ws, out);
}

// Round 4
// 64.246 us; speedup vs baseline: 1.7079x; 1.0134x over previous
//
#include <hip/hip_runtime.h>

#define S_DIM 64
#define B_DIM 256
#define D_DIM 1024
#define BS (B_DIM * S_DIM)        /* 16384 */
#define LP (B_DIM * (S_DIM - 1)) /* 16128 */
#define NB2 256                   /* blocks in pair_kernel */
#define CH 4                      /* rows per wave in row_stats */

__device__ __forceinline__ float wave_red(float v) {
#pragma unroll
  for (int o = 32; o > 0; o >>= 1) v += __shfl_down(v, o, 64);
  return v;
}

__device__ __forceinline__ float bfly_red(float v) {
#pragma unroll
  for (int o = 1; o < 64; o <<= 1) v += __shfl_xor(v, o, 64);
  return v;
}

__device__ __forceinline__ float dot4(float4 a, float4 b) {
  return a.x * b.x + a.y * b.y + a.z * b.z + a.w * b.w;
}

// ---------------------------------------------------------------------------
// Kernel 1: per-row reductions over D. One WAVE per 4-row s-chunk of one
// batch; wave-autonomous (no __syncthreads), prev row carried in registers,
// next row prefetched before the reduce of the current row.
// ws layout (floats): nl2[BS] | nt2[BS] | lt[BS] | ajl[BS] | ajt[BS] | partial[6*NB2]
// ---------------------------------------------------------------------------
__global__ __launch_bounds__(256) void row_stats_kernel(
    const float* __restrict__ logits, const float* __restrict__ tgt,
    float* __restrict__ ws) {
  const int tid = threadIdx.x;
  const int lane = tid & 63;
  const int gw = (blockIdx.x << 2) | (tid >> 6);  // global wave id, 0..4095
  const int b = gw >> 4;                          // batch
  const int s0 = (gw & 15) << 2;                  // first row of chunk

  float* nl2 = ws;
  float* nt2 = ws + BS;
  float* lt  = ws + 2 * BS;
  float* ajl = ws + 3 * BS;
  float* ajt = ws + 4 * BS;

  float4 pl[4], pt[4], cl[4], ct[4];

  // prev row (s0-1) or zeros
  if (s0 > 0) {
    const float4* Lp = reinterpret_cast<const float4*>(
        logits + ((size_t)(s0 - 1) * B_DIM + b) * D_DIM);
    const float4* Tp = reinterpret_cast<const float4*>(
        tgt + ((size_t)(s0 - 1) * B_DIM + b) * D_DIM);
#pragma unroll
    for (int j = 0; j < 4; ++j) {
      pl[j] = Lp[lane + 64 * j];
      pt[j] = Tp[lane + 64 * j];
    }
  } else {
#pragma unroll
    for (int j = 0; j < 4; ++j) {
      pl[j] = make_float4(0.f, 0.f, 0.f, 0.f);
      pt[j] = make_float4(0.f, 0.f, 0.f, 0.f);
    }
  }
  // current row (s0)
  {
    const float4* Lp = reinterpret_cast<const float4*>(
        logits + ((size_t)s0 * B_DIM + b) * D_DIM);
    const float4* Tp = reinterpret_cast<const float4*>(
        tgt + ((size_t)s0 * B_DIM + b) * D_DIM);
#pragma unroll
    for (int j = 0; j < 4; ++j) {
      cl[j] = Lp[lane + 64 * j];
      ct[j] = Tp[lane + 64 * j];
    }
  }

#pragma unroll 1
  for (int k = 0; k < CH; ++k) {
    const int s = s0 + k;
    // Prefetch next row BEFORE the reduce of the current row.
    float4 nl_[4], nt_[4];
    if (k < CH - 1) {
      const float4* Lp = reinterpret_cast<const float4*>(
          logits + ((size_t)(s + 1) * B_DIM + b) * D_DIM);
      const float4* Tp = reinterpret_cast<const float4*>(
          tgt + ((size_t)(s + 1) * B_DIM + b) * D_DIM);
#pragma unroll
      for (int j = 0; j < 4; ++j) {
        nl_[j] = Lp[lane + 64 * j];
        nt_[j] = Tp[lane + 64 * j];
      }
    }

    float v0 = 0.f, v1 = 0.f, v2 = 0.f, v3 = 0.f, v4 = 0.f;
#pragma unroll
    for (int j = 0; j < 4; ++j) {
      v0 += dot4(cl[j], cl[j]);
      v1 += dot4(ct[j], ct[j]);
      v2 += dot4(cl[j], ct[j]);
      v3 += dot4(cl[j], pl[j]);
      v4 += dot4(ct[j], pt[j]);
    }
    v0 = bfly_red(v0); v1 = bfly_red(v1); v2 = bfly_red(v2);
    v3 = bfly_red(v3); v4 = bfly_red(v4);

    const int i = b * S_DIM + s;
    if      (lane == 0) nl2[i] = v0;
    else if (lane == 1) nt2[i] = v1;
    else if (lane == 2) lt[i]  = v2;
    else if (lane == 3) { if (s > 0) ajl[i - 1] = v3; }
    else if (lane == 4) { if (s > 0) ajt[i - 1] = v4; }

    if (k < CH - 1) {
#pragma unroll
      for (int j = 0; j < 4; ++j) {
        pl[j] = cl[j]; pt[j] = ct[j];
        cl[j] = nl_[j]; ct[j] = nt_[j];
      }
    }
  }
}

// ---------------------------------------------------------------------------
// Kernel 2: per-row mask sums + per-pair delta/dd terms. 256 blocks x 64 thr,
// one row and one pair per thread; dd handled by next-valid-pair search.
// ---------------------------------------------------------------------------
__global__ __launch_bounds__(64) void pair_kernel(
    const unsigned char* __restrict__ mask, float* __restrict__ ws) {
  const float* nl2 = ws;
  const float* nt2 = ws + BS;
  const float* lt  = ws + 2 * BS;
  const float* ajl = ws + 3 * BS;
  const float* ajt = ws + 4 * BS;
  float* partial = ws + 5 * BS;

  __shared__ int s_flag;
  const int tid = threadIdx.x;
  if (tid == 0) s_flag = 0;
  __syncthreads();
  // Detect mask element width (byte vs 4-byte). For 4-byte storage, bytes at
  // index 1 mod 4 are always 0; for random byte masks some are 1.
  int any = 0;
  for (int i = tid; i < 4096; i += 64)
    if ((i & 3) == 1 && mask[i]) any = 1;
  if (any) s_flag = 1;
  __syncthreads();
  const bool isbyte = (s_flag != 0);

  const int gid = blockIdx.x * 64 + tid;

  float nv = 0.f, mse = 0.f, coss = 0.f, dsum = 0.f, ddsum = 0.f, cntf = 0.f;

  // Row terms.
  if (mask[isbyte ? gid : (gid << 2)] == 0) {
    float a = nl2[gid], q = nt2[gid], c = lt[gid];
    nv = 1.f;
    mse = a + q - 2.f * c;
    coss = 1.f - c / (fmaxf(sqrtf(a), 1e-8f) * fmaxf(sqrtf(q), 1e-8f));
  }

  // Pair terms.
  if (gid < LP) {
    const int b = gid / 63;
    const int s = gid - b * 63;
    const int i0 = b * S_DIM + s;
    bool pv = (mask[isbyte ? i0 : (i0 << 2)] == 0) &&
              (mask[isbyte ? (i0 + 1) : ((i0 + 1) << 2)] == 0);
    if (pv) {
      float dl = ajl[i0] / (fmaxf(sqrtf(nl2[i0]), 1e-6f) *
                            fmaxf(sqrtf(nl2[i0 + 1]), 1e-6f));
      float dt = ajt[i0] / (fmaxf(sqrtf(nt2[i0]), 1e-6f) *
                            fmaxf(sqrtf(nt2[i0 + 1]), 1e-6f));
      float w = dl - dt;
      dsum = w * w;
      cntf = 1.f;
      // Find the next valid pair in flattened order -> dd term.
      for (int p = gid + 1; p < LP; ++p) {
        int bq = p / 63;
        int sq = p - bq * 63;
        int j0 = bq * S_DIM + sq;
        bool qv = (mask[isbyte ? j0 : (j0 << 2)] == 0) &&
                  (mask[isbyte ? (j0 + 1) : ((j0 + 1) << 2)] == 0);
        if (qv) {
          float dlq = ajl[j0] / (fmaxf(sqrtf(nl2[j0]), 1e-6f) *
                                 fmaxf(sqrtf(nl2[j0 + 1]), 1e-6f));
          float dtq = ajt[j0] / (fmaxf(sqrtf(nt2[j0]), 1e-6f) *
                                 fmaxf(sqrtf(nt2[j0 + 1]), 1e-6f));
          float ddl = (dlq - dl) / ((dl != 0.f) ? dl : 1e-6f);
          float ddt = (dtq - dt) / ((dt != 0.f) ? dt : 1e-6f);
          float u = ddl - ddt;
          ddsum = u * u;
          break;
        }
      }
    }
  }

  nv = wave_red(nv); mse = wave_red(mse); coss = wave_red(coss);
  dsum = wave_red(dsum); ddsum = wave_red(ddsum); cntf = wave_red(cntf);
  if (tid == 0) {
    partial[0 * NB2 + blockIdx.x] = nv;
    partial[1 * NB2 + blockIdx.x] = mse;
    partial[2 * NB2 + blockIdx.x] = coss;
    partial[3 * NB2 + blockIdx.x] = dsum;
    partial[4 * NB2 + blockIdx.x] = ddsum;
    partial[5 * NB2 + blockIdx.x] = cntf;
  }
}

// ---------------------------------------------------------------------------
// Kernel 3: combine the 256 partials into the scalar loss.
// ---------------------------------------------------------------------------
__global__ __launch_bounds__(256) void final_combine_kernel(
    const float* __restrict__ ws, float* __restrict__ out) {
  const float* partial = ws + 5 * BS;
  __shared__ float sm[4];
  const int tid = threadIdx.x;
  float acc[6];
#pragma unroll
  for (int k = 0; k < 6; ++k) {
    float v = partial[k * NB2 + tid];
    v = wave_red(v);
    __syncthreads();
    if ((tid & 63) == 0) sm[tid >> 6] = v;
    __syncthreads();
    float r = 0.f;
    if (tid < 4) r = sm[tid];
    r = wave_red(r);
    acc[k] = r;
  }
  if (tid == 0) {
    float nv = acc[0], mse = acc[1], coss = acc[2];
    float dsum = acc[3], ddsum = acc[4], cnt = acc[5];
    float loss = mse / (nv * (float)D_DIM)
               + coss / nv
               + dsum / fmaxf(cnt, 1.f)
               + (ddsum / fmaxf(cnt - 1.f, 1.f)) * 0.01f;
    out[0] = loss;
  }
}

extern "C" void kernel_launch(void* const* d_in, const int* in_sizes, int n_in,
                              void* d_out, int out_size, void* d_ws, size_t ws_size,
                              hipStream_t stream) {
  const float* logits = (const float*)d_in[0];
  const float* tgt    = (const float*)d_in[1];
  const unsigned char* mask = (const unsigned char*)d_in[2];
  float* out = (float*)d_out;
  float* ws  = (float*)d_ws;

  row_stats_kernel<<<dim3(BS / CH / 4), dim3(256), 0, stream>>>(logits, tgt, ws);
  pair_kernel<<<dim3(NB2), dim3(64), 0, stream>>>(mask, ws);
  final_combine_kernel<<<dim3(1), dim3(256), 0, stream>>>(ws, out);
}

// Round 5
// 41.536 us; speedup vs baseline: 2.6418x; 1.5467x over previous
//
#include <hip/hip_runtime.h>

#define S_DIM 64
#define B_DIM 256
#define D_DIM 1024
#define BS (B_DIM * S_DIM)        /* 16384 */
#define LP (B_DIM * (S_DIM - 1)) /* 16128 */
#define NBP 128                   /* blocks in pair_kernel */

__device__ __forceinline__ float dot4(float4 a, float4 b) {
  return a.x * b.x + a.y * b.y + a.z * b.z + a.w * b.w;
}

// DPP row_ror add (pure VALU, no LDS): sums within each 16-lane row, then
// readlane-finish across the 4 rows. Returns wave-uniform sum of all 64 lanes.
template <int CTRL>
__device__ __forceinline__ float dpp_add(float v) {
  int r = __builtin_amdgcn_update_dpp(__float_as_int(v), __float_as_int(v),
                                      CTRL, 0xF, 0xF, false);
  return v + __int_as_float(r);
}

__device__ __forceinline__ float red64_uni(float v) {
  v = dpp_add<0x128>(v);  // row_ror:8
  v = dpp_add<0x124>(v);  // row_ror:4
  v = dpp_add<0x122>(v);  // row_ror:2
  v = dpp_add<0x121>(v);  // row_ror:1
  float r = __int_as_float(__builtin_amdgcn_readlane(__float_as_int(v), 0));
  r += __int_as_float(__builtin_amdgcn_readlane(__float_as_int(v), 16));
  r += __int_as_float(__builtin_amdgcn_readlane(__float_as_int(v), 32));
  r += __int_as_float(__builtin_amdgcn_readlane(__float_as_int(v), 48));
  return r;
}

// ---------------------------------------------------------------------------
// Kernel 1: per-row reductions. One wave per 2 rows; prev row reused for the
// adjacent dot; next row prefetched into the dead prev registers. No LDS,
// no __syncthreads, DPP+readlane reductions. XCD-chunked block swizzle so
// the overlap row is L2-local.
// ws layout (floats): nl2[BS] | nt2[BS] | lt[BS] | ajl[BS] | ajt[BS] | partial[6*NBP]
// ---------------------------------------------------------------------------
__global__ __launch_bounds__(256) void row_stats_kernel(
    const float* __restrict__ logits, const float* __restrict__ tgt,
    float* __restrict__ ws) {
  const int tid = threadIdx.x;
  const int lane = tid & 63;
  int blk = blockIdx.x;
  blk = (blk & 7) * 256 + (blk >> 3);      // bijective: 2048 % 8 == 0
  const int gw = (blk << 2) | (tid >> 6);  // 0..8191
  const int b  = gw >> 5;                  // batch
  const int s0 = (gw & 31) << 1;           // row chunk base: 0,2,..,62

  float* nl2 = ws;
  float* nt2 = ws + BS;
  float* lt  = ws + 2 * BS;
  float* ajl = ws + 3 * BS;
  float* ajt = ws + 4 * BS;

  float4 P[8], C[8];  // [0..3]=logits row, [4..7]=tgt row

  auto ldrow = [&](int s, float4* dst) {
    const float4* Lp = reinterpret_cast<const float4*>(
        logits + ((size_t)s * B_DIM + b) * D_DIM);
    const float4* Tp = reinterpret_cast<const float4*>(
        tgt + ((size_t)s * B_DIM + b) * D_DIM);
#pragma unroll
    for (int j = 0; j < 4; ++j) dst[j] = Lp[lane + 64 * j];
#pragma unroll
    for (int j = 0; j < 4; ++j) dst[4 + j] = Tp[lane + 64 * j];
  };

  if (s0 > 0) {
    ldrow(s0 - 1, P);
  } else {
#pragma unroll
    for (int j = 0; j < 8; ++j) P[j] = make_float4(0.f, 0.f, 0.f, 0.f);
  }
  ldrow(s0, C);

  // ---- row s0 (cur=C, prev=P)
  float a0 = 0.f, a1 = 0.f, a2 = 0.f, a3 = 0.f, a4 = 0.f;
#pragma unroll
  for (int j = 0; j < 4; ++j) {
    a0 += dot4(C[j], C[j]);
    a1 += dot4(C[4 + j], C[4 + j]);
    a2 += dot4(C[j], C[4 + j]);
    a3 += dot4(C[j], P[j]);
    a4 += dot4(C[4 + j], P[4 + j]);
  }
  ldrow(s0 + 1, P);  // prefetch next row; P already consumed
  a0 = red64_uni(a0); a1 = red64_uni(a1); a2 = red64_uni(a2);
  a3 = red64_uni(a3); a4 = red64_uni(a4);
  {
    const int i = b * S_DIM + s0;
    if (lane == 0) {
      nl2[i] = a0; nt2[i] = a1; lt[i] = a2;
      if (s0 > 0) { ajl[i - 1] = a3; ajt[i - 1] = a4; }
    }
  }

  // ---- row s0+1 (cur=P, prev=C)
  float b0 = 0.f, b1 = 0.f, b2 = 0.f, b3 = 0.f, b4 = 0.f;
#pragma unroll
  for (int j = 0; j < 4; ++j) {
    b0 += dot4(P[j], P[j]);
    b1 += dot4(P[4 + j], P[4 + j]);
    b2 += dot4(P[j], P[4 + j]);
    b3 += dot4(P[j], C[j]);
    b4 += dot4(P[4 + j], C[4 + j]);
  }
  b0 = red64_uni(b0); b1 = red64_uni(b1); b2 = red64_uni(b2);
  b3 = red64_uni(b3); b4 = red64_uni(b4);
  {
    const int i = b * S_DIM + s0 + 1;
    if (lane == 0) {
      nl2[i] = b0; nt2[i] = b1; lt[i] = b2;
      ajl[i - 1] = b3; ajt[i - 1] = b4;  // s0+1 >= 1 always
    }
  }
}

// ---------------------------------------------------------------------------
// Kernel 2: mask-weighted row sums + pair delta/dd terms. 128 blocks x 128
// threads. A ballot-built 16-batch validity bitmap in LDS turns the
// next-valid-pair search into a bit scan.
// ---------------------------------------------------------------------------
__global__ __launch_bounds__(128) void pair_kernel(
    const unsigned char* __restrict__ mask, float* __restrict__ ws) {
  const float* nl2 = ws;
  const float* nt2 = ws + BS;
  const float* lt  = ws + 2 * BS;
  const float* ajl = ws + 3 * BS;
  const float* ajt = ws + 4 * BS;
  float* partial = ws + 5 * BS;

  __shared__ unsigned long long vb[16];
  __shared__ float psum[6][2];
  __shared__ int s_flag;

  const int tid = threadIdx.x;
  const int w = tid >> 6, lane = tid & 63;

  if (tid == 0) s_flag = 0;
  __syncthreads();
  int any = 0;
  for (int i = tid; i < 1024; i += 128)
    if ((i & 3) == 1 && mask[i]) any = 1;
  if (any) s_flag = 1;
  __syncthreads();
  const bool isbyte = (s_flag != 0);

  int B0 = (blockIdx.x * 128) / 63;
  if (B0 > B_DIM - 16) B0 = B_DIM - 16;

  // Build per-batch row-validity bitmaps for batches [B0, B0+16) via ballot.
#pragma unroll
  for (int k = 0; k < 8; ++k) {
    const int q = k * 2 + w;
    const int g2 = (B0 + q) * 64 + lane;
    bool val = mask[isbyte ? g2 : (g2 << 2)] == 0;
    unsigned long long bal = __ballot(val);
    if (lane == 0) vb[q] = bal;
  }
  __syncthreads();

  const int g = blockIdx.x * 128 + tid;  // row id and pair id

  float nv = 0.f, mse = 0.f, coss = 0.f, dsum = 0.f, ddsum = 0.f, cntf = 0.f;

  // Row terms.
  if (mask[isbyte ? g : (g << 2)] == 0) {
    float A = nl2[g], Q = nt2[g], Cc = lt[g];
    nv = 1.f;
    mse = A + Q - 2.f * Cc;
    coss = 1.f - Cc / (fmaxf(sqrtf(A), 1e-8f) * fmaxf(sqrtf(Q), 1e-8f));
  }

  // Pair terms.
  if (g < LP) {
    const int b = g / 63;
    const int s = g - b * 63;
    const unsigned long long pbb = vb[b - B0] & (vb[b - B0] >> 1);
    if ((pbb >> s) & 1ull) {
      const int i0 = b * S_DIM + s;
      float dl = ajl[i0] / (fmaxf(sqrtf(nl2[i0]), 1e-6f) *
                            fmaxf(sqrtf(nl2[i0 + 1]), 1e-6f));
      float dt = ajt[i0] / (fmaxf(sqrtf(nt2[i0]), 1e-6f) *
                            fmaxf(sqrtf(nt2[i0 + 1]), 1e-6f));
      float wv = dl - dt;
      dsum = wv * wv;
      cntf = 1.f;

      // Next valid pair: bit scan through the LDS window.
      int bq = b, sq = -1;
      bool found = false, fellback = false;
      unsigned long long cur = pbb & (~0ull << (s + 1));
      while (true) {
        if (cur) { sq = __builtin_ctzll(cur); found = true; break; }
        ++bq;
        if (bq >= B_DIM) break;
        if (bq - B0 < 16) {
          cur = vb[bq - B0] & (vb[bq - B0] >> 1);
        } else {
          fellback = true;
          break;
        }
      }
      if (fellback) {  // correctness fallback; ~never taken for random masks
        while (bq < B_DIM && !found) {
          for (int s2 = 0; s2 < 63; ++s2) {
            int r0 = bq * S_DIM + s2;
            bool v1 = mask[isbyte ? r0 : (r0 << 2)] == 0;
            bool v2 = mask[isbyte ? (r0 + 1) : ((r0 + 1) << 2)] == 0;
            if (v1 && v2) { sq = s2; found = true; break; }
          }
          if (!found) ++bq;
        }
      }
      if (found) {
        const int j0 = bq * S_DIM + sq;
        float dlq = ajl[j0] / (fmaxf(sqrtf(nl2[j0]), 1e-6f) *
                               fmaxf(sqrtf(nl2[j0 + 1]), 1e-6f));
        float dtq = ajt[j0] / (fmaxf(sqrtf(nt2[j0]), 1e-6f) *
                               fmaxf(sqrtf(nt2[j0 + 1]), 1e-6f));
        float ddl = (dlq - dl) / ((dl != 0.f) ? dl : 1e-6f);
        float ddt = (dtq - dt) / ((dt != 0.f) ? dt : 1e-6f);
        float u = ddl - ddt;
        ddsum = u * u;
      }
    }
  }

  float vals[6] = {nv, mse, coss, dsum, ddsum, cntf};
#pragma unroll
  for (int k2 = 0; k2 < 6; ++k2) {
    float v = red64_uni(vals[k2]);
    if (lane == 0) psum[k2][w] = v;
  }
  __syncthreads();
  if (tid == 0) {
#pragma unroll
    for (int k2 = 0; k2 < 6; ++k2)
      partial[k2 * NBP + blockIdx.x] = psum[k2][0] + psum[k2][1];
  }
}

// ---------------------------------------------------------------------------
// Kernel 3: combine 128 partials into the scalar loss.
// ---------------------------------------------------------------------------
__global__ __launch_bounds__(128) void final_combine_kernel(
    const float* __restrict__ ws, float* __restrict__ out) {
  const float* partial = ws + 5 * BS;
  __shared__ float sm[6][2];
  const int tid = threadIdx.x, w = tid >> 6, lane = tid & 63;
#pragma unroll
  for (int k = 0; k < 6; ++k) {
    float v = red64_uni(partial[k * NBP + tid]);
    if (lane == 0) sm[k][w] = v;
  }
  __syncthreads();
  if (tid == 0) {
    float nv   = sm[0][0] + sm[0][1];
    float mse  = sm[1][0] + sm[1][1];
    float coss = sm[2][0] + sm[2][1];
    float dsum = sm[3][0] + sm[3][1];
    float ddsm = sm[4][0] + sm[4][1];
    float cnt  = sm[5][0] + sm[5][1];
    out[0] = mse / (nv * (float)D_DIM) + coss / nv +
             dsum / fmaxf(cnt, 1.f) + (ddsm / fmaxf(cnt - 1.f, 1.f)) * 0.01f;
  }
}

extern "C" void kernel_launch(void* const* d_in, const int* in_sizes, int n_in,
                              void* d_out, int out_size, void* d_ws, size_t ws_size,
                              hipStream_t stream) {
  const float* logits = (const float*)d_in[0];
  const float* tgt    = (const float*)d_in[1];
  const unsigned char* mask = (const unsigned char*)d_in[2];
  float* out = (float*)d_out;
  float* ws  = (float*)d_ws;

  row_stats_kernel<<<dim3(2048), dim3(256), 0, stream>>>(logits, tgt, ws);
  pair_kernel<<<dim3(NBP), dim3(128), 0, stream>>>(mask, ws);
  final_combine_kernel<<<dim3(1), dim3(128), 0, stream>>>(ws, out);
}

// Round 6
// 37.414 us; speedup vs baseline: 2.9328x; 1.1102x over previous
//
#include <hip/hip_runtime.h>

#define S_DIM 64
#define B_DIM 256
#define D_DIM 1024
#define BS (B_DIM * S_DIM)        /* 16384 */
#define LP (B_DIM * (S_DIM - 1)) /* 16128 */
#define NBP 128                   /* blocks in pair_kernel */

__device__ __forceinline__ float dot4(float4 a, float4 b) {
  return a.x * b.x + a.y * b.y + a.z * b.z + a.w * b.w;
}

// DPP row_ror add (pure VALU, no LDS) + readlane finish.
template <int CTRL>
__device__ __forceinline__ float dpp_add(float v) {
  int r = __builtin_amdgcn_update_dpp(__float_as_int(v), __float_as_int(v),
                                      CTRL, 0xF, 0xF, false);
  return v + __int_as_float(r);
}

__device__ __forceinline__ float red64_uni(float v) {
  v = dpp_add<0x128>(v);  // row_ror:8
  v = dpp_add<0x124>(v);  // row_ror:4
  v = dpp_add<0x122>(v);  // row_ror:2
  v = dpp_add<0x121>(v);  // row_ror:1
  float r = __int_as_float(__builtin_amdgcn_readlane(__float_as_int(v), 0));
  r += __int_as_float(__builtin_amdgcn_readlane(__float_as_int(v), 16));
  r += __int_as_float(__builtin_amdgcn_readlane(__float_as_int(v), 32));
  r += __int_as_float(__builtin_amdgcn_readlane(__float_as_int(v), 48));
  return r;
}

// ---------------------------------------------------------------------------
// Kernel 1: per-row reductions, D split across TWO waves per row (h=0,1).
// One wave per {batch b, rows s0,s0+1, d-half h}: 16384 waves total. Lane
// owns 2 float4 per tensor per row; prev row carried in regs for adjacent
// dots; next row prefetched into dead regs. No LDS, no __syncthreads.
// ws layout (floats): nl2p[2BS] | nt2p[2BS] | ltp[2BS] | ajlp[2BS] | ajtp[2BS]
//                     | partial[6*NBP]
// Half-partials stored at [2*rowid + h]; pair_kernel sums the two halves.
// ---------------------------------------------------------------------------
__global__ __launch_bounds__(256) void row_stats_kernel(
    const float* __restrict__ logits, const float* __restrict__ tgt,
    float* __restrict__ ws) {
  const int tid = threadIdx.x;
  const int lane = tid & 63;
  int blk = blockIdx.x;
  blk = (blk & 7) * 512 + (blk >> 3);      // bijective: 4096 % 8 == 0
  const int gw = (blk << 2) | (tid >> 6);  // 0..16383
  const int h  = gw & 1;                   // d-half
  const int s0 = ((gw >> 1) & 31) << 1;    // 0,2,...,62
  const int b  = gw >> 6;                  // batch

  float* nl2p = ws;
  float* nt2p = ws + 2 * BS;
  float* ltp  = ws + 4 * BS;
  float* ajlp = ws + 6 * BS;
  float* ajtp = ws + 8 * BS;

  const int fo = h * 128 + lane;  // float4 index within row (+64 for j=1)

  float4 P[4], C[4];  // [0..1]=logits(j=0,1), [2..3]=tgt(j=0,1)

  auto ldrow = [&](int s, float4* dst) {
    const float4* Lp = reinterpret_cast<const float4*>(
        logits + ((size_t)s * B_DIM + b) * D_DIM);
    const float4* Tp = reinterpret_cast<const float4*>(
        tgt + ((size_t)s * B_DIM + b) * D_DIM);
    dst[0] = Lp[fo];
    dst[1] = Lp[fo + 64];
    dst[2] = Tp[fo];
    dst[3] = Tp[fo + 64];
  };

  if (s0 > 0) {
    ldrow(s0 - 1, P);
  } else {
#pragma unroll
    for (int j = 0; j < 4; ++j) P[j] = make_float4(0.f, 0.f, 0.f, 0.f);
  }
  ldrow(s0, C);

  // ---- row s0 (cur=C, prev=P)
  float a0 = dot4(C[0], C[0]) + dot4(C[1], C[1]);
  float a1 = dot4(C[2], C[2]) + dot4(C[3], C[3]);
  float a2 = dot4(C[0], C[2]) + dot4(C[1], C[3]);
  float a3 = dot4(C[0], P[0]) + dot4(C[1], P[1]);
  float a4 = dot4(C[2], P[2]) + dot4(C[3], P[3]);
  ldrow(s0 + 1, P);  // prefetch next row into dead prev regs
  a0 = red64_uni(a0); a1 = red64_uni(a1); a2 = red64_uni(a2);
  a3 = red64_uni(a3); a4 = red64_uni(a4);
  {
    const int i = b * S_DIM + s0;
    if (lane == 0) {
      nl2p[2 * i + h] = a0; nt2p[2 * i + h] = a1; ltp[2 * i + h] = a2;
      if (s0 > 0) { ajlp[2 * (i - 1) + h] = a3; ajtp[2 * (i - 1) + h] = a4; }
    }
  }

  // ---- row s0+1 (cur=P, prev=C)
  float b0 = dot4(P[0], P[0]) + dot4(P[1], P[1]);
  float b1 = dot4(P[2], P[2]) + dot4(P[3], P[3]);
  float b2 = dot4(P[0], P[2]) + dot4(P[1], P[3]);
  float b3 = dot4(P[0], C[0]) + dot4(P[1], C[1]);
  float b4 = dot4(P[2], C[2]) + dot4(P[3], C[3]);
  b0 = red64_uni(b0); b1 = red64_uni(b1); b2 = red64_uni(b2);
  b3 = red64_uni(b3); b4 = red64_uni(b4);
  {
    const int i = b * S_DIM + s0 + 1;
    if (lane == 0) {
      nl2p[2 * i + h] = b0; nt2p[2 * i + h] = b1; ltp[2 * i + h] = b2;
      ajlp[2 * (i - 1) + h] = b3; ajtp[2 * (i - 1) + h] = b4;
    }
  }
}

// Sum the two d-half partials with one float2 load.
__device__ __forceinline__ float ld2(const float* p, int i) {
  float2 v = reinterpret_cast<const float2*>(p)[i];
  return v.x + v.y;
}

// ---------------------------------------------------------------------------
// Kernel 2: mask-weighted row sums + pair delta/dd terms. 128 blocks x 128
// threads; ballot-built validity bitmaps make the next-valid-pair search a
// bit scan.
// ---------------------------------------------------------------------------
__global__ __launch_bounds__(128) void pair_kernel(
    const unsigned char* __restrict__ mask, float* __restrict__ ws) {
  const float* nl2p = ws;
  const float* nt2p = ws + 2 * BS;
  const float* ltp  = ws + 4 * BS;
  const float* ajlp = ws + 6 * BS;
  const float* ajtp = ws + 8 * BS;
  float* partial = ws + 10 * BS;

  __shared__ unsigned long long vb[16];
  __shared__ float psum[6][2];
  __shared__ int s_flag;

  const int tid = threadIdx.x;
  const int w = tid >> 6, lane = tid & 63;

  if (tid == 0) s_flag = 0;
  __syncthreads();
  int any = 0;
  for (int i = tid; i < 1024; i += 128)
    if ((i & 3) == 1 && mask[i]) any = 1;
  if (any) s_flag = 1;
  __syncthreads();
  const bool isbyte = (s_flag != 0);

  int B0 = (blockIdx.x * 128) / 63;
  if (B0 > B_DIM - 16) B0 = B_DIM - 16;

#pragma unroll
  for (int k = 0; k < 8; ++k) {
    const int q = k * 2 + w;
    const int g2 = (B0 + q) * 64 + lane;
    bool val = mask[isbyte ? g2 : (g2 << 2)] == 0;
    unsigned long long bal = __ballot(val);
    if (lane == 0) vb[q] = bal;
  }
  __syncthreads();

  const int g = blockIdx.x * 128 + tid;  // row id and pair id

  float nv = 0.f, mse = 0.f, coss = 0.f, dsum = 0.f, ddsum = 0.f, cntf = 0.f;

  // Row terms.
  if (mask[isbyte ? g : (g << 2)] == 0) {
    float A = ld2(nl2p, g), Q = ld2(nt2p, g), Cc = ld2(ltp, g);
    nv = 1.f;
    mse = A + Q - 2.f * Cc;
    coss = 1.f - Cc / (fmaxf(sqrtf(A), 1e-8f) * fmaxf(sqrtf(Q), 1e-8f));
  }

  // Pair terms.
  if (g < LP) {
    const int b = g / 63;
    const int s = g - b * 63;
    const unsigned long long pbb = vb[b - B0] & (vb[b - B0] >> 1);
    if ((pbb >> s) & 1ull) {
      const int i0 = b * S_DIM + s;
      float dl = ld2(ajlp, i0) / (fmaxf(sqrtf(ld2(nl2p, i0)), 1e-6f) *
                                  fmaxf(sqrtf(ld2(nl2p, i0 + 1)), 1e-6f));
      float dt = ld2(ajtp, i0) / (fmaxf(sqrtf(ld2(nt2p, i0)), 1e-6f) *
                                  fmaxf(sqrtf(ld2(nt2p, i0 + 1)), 1e-6f));
      float wv = dl - dt;
      dsum = wv * wv;
      cntf = 1.f;

      // Next valid pair: bit scan through the LDS window.
      int bq = b, sq = -1;
      bool found = false, fellback = false;
      unsigned long long cur = pbb & (~0ull << (s + 1));
      while (true) {
        if (cur) { sq = __builtin_ctzll(cur); found = true; break; }
        ++bq;
        if (bq >= B_DIM) break;
        if (bq - B0 < 16) {
          cur = vb[bq - B0] & (vb[bq - B0] >> 1);
        } else {
          fellback = true;
          break;
        }
      }
      if (fellback) {  // correctness fallback; ~never taken for random masks
        while (bq < B_DIM && !found) {
          for (int s2 = 0; s2 < 63; ++s2) {
            int r0 = bq * S_DIM + s2;
            bool v1 = mask[isbyte ? r0 : (r0 << 2)] == 0;
            bool v2 = mask[isbyte ? (r0 + 1) : ((r0 + 1) << 2)] == 0;
            if (v1 && v2) { sq = s2; found = true; break; }
          }
          if (!found) ++bq;
        }
      }
      if (found) {
        const int j0 = bq * S_DIM + sq;
        float dlq = ld2(ajlp, j0) / (fmaxf(sqrtf(ld2(nl2p, j0)), 1e-6f) *
                                     fmaxf(sqrtf(ld2(nl2p, j0 + 1)), 1e-6f));
        float dtq = ld2(ajtp, j0) / (fmaxf(sqrtf(ld2(nt2p, j0)), 1e-6f) *
                                     fmaxf(sqrtf(ld2(nt2p, j0 + 1)), 1e-6f));
        float ddl = (dlq - dl) / ((dl != 0.f) ? dl : 1e-6f);
        float ddt = (dtq - dt) / ((dt != 0.f) ? dt : 1e-6f);
        float u = ddl - ddt;
        ddsum = u * u;
      }
    }
  }

  float vals[6] = {nv, mse, coss, dsum, ddsum, cntf};
#pragma unroll
  for (int k2 = 0; k2 < 6; ++k2) {
    float v = red64_uni(vals[k2]);
    if (lane == 0) psum[k2][w] = v;
  }
  __syncthreads();
  if (tid == 0) {
#pragma unroll
    for (int k2 = 0; k2 < 6; ++k2)
      partial[k2 * NBP + blockIdx.x] = psum[k2][0] + psum[k2][1];
  }
}

// ---------------------------------------------------------------------------
// Kernel 3: combine 128 partials into the scalar loss.
// ---------------------------------------------------------------------------
__global__ __launch_bounds__(128) void final_combine_kernel(
    const float* __restrict__ ws, float* __restrict__ out) {
  const float* partial = ws + 10 * BS;
  __shared__ float sm[6][2];
  const int tid = threadIdx.x, w = tid >> 6, lane = tid & 63;
#pragma unroll
  for (int k = 0; k < 6; ++k) {
    float v = red64_uni(partial[k * NBP + tid]);
    if (lane == 0) sm[k][w] = v;
  }
  __syncthreads();
  if (tid == 0) {
    float nv   = sm[0][0] + sm[0][1];
    float mse  = sm[1][0] + sm[1][1];
    float coss = sm[2][0] + sm[2][1];
    float dsum = sm[3][0] + sm[3][1];
    float ddsm = sm[4][0] + sm[4][1];
    float cnt  = sm[5][0] + sm[5][1];
    out[0] = mse / (nv * (float)D_DIM) + coss / nv +
             dsum / fmaxf(cnt, 1.f) + (ddsm / fmaxf(cnt - 1.f, 1.f)) * 0.01f;
  }
}

extern "C" void kernel_launch(void* const* d_in, const int* in_sizes, int n_in,
                              void* d_out, int out_size, void* d_ws, size_t ws_size,
                              hipStream_t stream) {
  const float* logits = (const float*)d_in[0];
  const float* tgt    = (const float*)d_in[1];
  const unsigned char* mask = (const unsigned char*)d_in[2];
  float* out = (float*)d_out;
  float* ws  = (float*)d_ws;

  row_stats_kernel<<<dim3(4096), dim3(256), 0, stream>>>(logits, tgt, ws);
  pair_kernel<<<dim3(NBP), dim3(128), 0, stream>>>(mask, ws);
  final_combine_kernel<<<dim3(1), dim3(128), 0, stream>>>(ws, out);
}

// Round 7
// 37.234 us; speedup vs baseline: 2.9470x; 1.0048x over previous
//
#include <hip/hip_runtime.h>

#define S_DIM 64
#define B_DIM 256
#define D_DIM 1024
#define BS (B_DIM * S_DIM)        /* 16384 */
#define LP (B_DIM * (S_DIM - 1)) /* 16128 */
#define NBP 128                   /* blocks in pair_kernel */

__device__ __forceinline__ float dot4(float4 a, float4 b) {
  return a.x * b.x + a.y * b.y + a.z * b.z + a.w * b.w;
}

// DPP row_ror add (pure VALU, no LDS) + readlane finish.
template <int CTRL>
__device__ __forceinline__ float dpp_add(float v) {
  int r = __builtin_amdgcn_update_dpp(__float_as_int(v), __float_as_int(v),
                                      CTRL, 0xF, 0xF, false);
  return v + __int_as_float(r);
}

__device__ __forceinline__ float red64_uni(float v) {
  v = dpp_add<0x128>(v);  // row_ror:8
  v = dpp_add<0x124>(v);  // row_ror:4
  v = dpp_add<0x122>(v);  // row_ror:2
  v = dpp_add<0x121>(v);  // row_ror:1
  float r = __int_as_float(__builtin_amdgcn_readlane(__float_as_int(v), 0));
  r += __int_as_float(__builtin_amdgcn_readlane(__float_as_int(v), 16));
  r += __int_as_float(__builtin_amdgcn_readlane(__float_as_int(v), 32));
  r += __int_as_float(__builtin_amdgcn_readlane(__float_as_int(v), 48));
  return r;
}

// ---------------------------------------------------------------------------
// Kernel 1: per-row reductions, D split across two waves per row (h=0,1).
// Block = 512 threads = 8 waves = 4 s-chunks x 2 halves covering 8 rows of
// one batch. Each wave loads ONLY its 2 half-rows; the chunk-boundary row is
// shared through LDS (one barrier), so only the block's first chunk reads an
// overlap row from global: logical traffic 144 MiB instead of 192 MiB.
// ws layout (floats): nl2p[2BS] | nt2p[2BS] | ltp[2BS] | ajlp[2BS] | ajtp[2BS]
//                     | partial[6*NBP]
// Half-partials at [2*rowid + h]; pair_kernel sums the halves.
// ---------------------------------------------------------------------------
__global__ __launch_bounds__(512) void row_stats_kernel(
    const float* __restrict__ logits, const float* __restrict__ tgt,
    float* __restrict__ ws) {
  const int tid = threadIdx.x;
  const int lane = tid & 63;
  const int wv = tid >> 6;            // wave in block, 0..7
  int bid = blockIdx.x;
  bid = (bid & 7) * 256 + (bid >> 3); // XCD swizzle, bijective (2048 % 8 == 0)
  const int b  = bid >> 3;            // batch
  const int r0 = (bid & 7) << 3;      // block row base: 0,8,...,56
  const int k  = wv >> 1;             // chunk in block, 0..3
  const int h  = wv & 1;              // d-half
  const int s0 = r0 + (k << 1);       // first row of this wave's chunk

  float* nl2p = ws;
  float* nt2p = ws + 2 * BS;
  float* ltp  = ws + 4 * BS;
  float* ajlp = ws + 6 * BS;
  float* ajtp = ws + 8 * BS;

  const int fo = h * 128 + lane;  // float4 index within row (+64 for j=1)

  // Per-wave LDS export of row s0+1: [0..127]=logits half, [128..255]=tgt half
  __shared__ float4 lds[8][256];

  float4 R[4], N[4], P[4];  // rows s0, s0+1, s0-1; [0..1]=logits, [2..3]=tgt

  auto ldrow = [&](int s, float4* dst) {
    const float4* Lp = reinterpret_cast<const float4*>(
        logits + ((size_t)s * B_DIM + b) * D_DIM);
    const float4* Tp = reinterpret_cast<const float4*>(
        tgt + ((size_t)s * B_DIM + b) * D_DIM);
    dst[0] = Lp[fo];
    dst[1] = Lp[fo + 64];
    dst[2] = Tp[fo];
    dst[3] = Tp[fo + 64];
  };

  ldrow(s0, R);
  ldrow(s0 + 1, N);
  if (k == 0) {  // first chunk in block: prev row comes from global (or zero)
    if (s0 > 0) {
      ldrow(s0 - 1, P);
    } else {
#pragma unroll
      for (int j = 0; j < 4; ++j) P[j] = make_float4(0.f, 0.f, 0.f, 0.f);
    }
  }

  // Export row s0+1 to LDS for the next chunk's waves.
  lds[wv][lane]       = N[0];
  lds[wv][lane + 64]  = N[1];
  lds[wv][lane + 128] = N[2];
  lds[wv][lane + 192] = N[3];

  // Pre-barrier: everything not involving P.
  float a0 = dot4(R[0], R[0]) + dot4(R[1], R[1]);
  float a1 = dot4(R[2], R[2]) + dot4(R[3], R[3]);
  float a2 = dot4(R[0], R[2]) + dot4(R[1], R[3]);
  float b0 = dot4(N[0], N[0]) + dot4(N[1], N[1]);
  float b1 = dot4(N[2], N[2]) + dot4(N[3], N[3]);
  float b2 = dot4(N[0], N[2]) + dot4(N[1], N[3]);
  float b3 = dot4(N[0], R[0]) + dot4(N[1], R[1]);  // aj[s0] logits
  float b4 = dot4(N[2], R[2]) + dot4(N[3], R[3]);  // aj[s0] tgt

  __syncthreads();

  if (k != 0) {  // prev row from the previous chunk's LDS export
    P[0] = lds[wv - 2][lane];
    P[1] = lds[wv - 2][lane + 64];
    P[2] = lds[wv - 2][lane + 128];
    P[3] = lds[wv - 2][lane + 192];
  }
  float a3 = dot4(R[0], P[0]) + dot4(R[1], P[1]);  // aj[s0-1] logits
  float a4 = dot4(R[2], P[2]) + dot4(R[3], P[3]);  // aj[s0-1] tgt

  a0 = red64_uni(a0); a1 = red64_uni(a1); a2 = red64_uni(a2);
  a3 = red64_uni(a3); a4 = red64_uni(a4);
  b0 = red64_uni(b0); b1 = red64_uni(b1); b2 = red64_uni(b2);
  b3 = red64_uni(b3); b4 = red64_uni(b4);

  if (lane == 0) {
    const int i = b * S_DIM + s0;
    nl2p[2 * i + h] = a0; nt2p[2 * i + h] = a1; ltp[2 * i + h] = a2;
    if (s0 > 0) { ajlp[2 * (i - 1) + h] = a3; ajtp[2 * (i - 1) + h] = a4; }
    const int i2 = i + 1;
    nl2p[2 * i2 + h] = b0; nt2p[2 * i2 + h] = b1; ltp[2 * i2 + h] = b2;
    ajlp[2 * i + h] = b3; ajtp[2 * i + h] = b4;
  }
}

// Sum the two d-half partials with one float2 load.
__device__ __forceinline__ float ld2(const float* p, int i) {
  float2 v = reinterpret_cast<const float2*>(p)[i];
  return v.x + v.y;
}

// ---------------------------------------------------------------------------
// Kernel 2: mask-weighted row sums + pair delta/dd terms. 128 blocks x 128
// threads; ballot-built validity bitmaps make the next-valid-pair search a
// bit scan.
// ---------------------------------------------------------------------------
__global__ __launch_bounds__(128) void pair_kernel(
    const unsigned char* __restrict__ mask, float* __restrict__ ws) {
  const float* nl2p = ws;
  const float* nt2p = ws + 2 * BS;
  const float* ltp  = ws + 4 * BS;
  const float* ajlp = ws + 6 * BS;
  const float* ajtp = ws + 8 * BS;
  float* partial = ws + 10 * BS;

  __shared__ unsigned long long vb[16];
  __shared__ float psum[6][2];
  __shared__ int s_flag;

  const int tid = threadIdx.x;
  const int w = tid >> 6, lane = tid & 63;

  if (tid == 0) s_flag = 0;
  __syncthreads();
  int any = 0;
  for (int i = tid; i < 1024; i += 128)
    if ((i & 3) == 1 && mask[i]) any = 1;
  if (any) s_flag = 1;
  __syncthreads();
  const bool isbyte = (s_flag != 0);

  int B0 = (blockIdx.x * 128) / 63;
  if (B0 > B_DIM - 16) B0 = B_DIM - 16;

#pragma unroll
  for (int k = 0; k < 8; ++k) {
    const int q = k * 2 + w;
    const int g2 = (B0 + q) * 64 + lane;
    bool val = mask[isbyte ? g2 : (g2 << 2)] == 0;
    unsigned long long bal = __ballot(val);
    if (lane == 0) vb[q] = bal;
  }
  __syncthreads();

  const int g = blockIdx.x * 128 + tid;  // row id and pair id

  float nv = 0.f, mse = 0.f, coss = 0.f, dsum = 0.f, ddsum = 0.f, cntf = 0.f;

  // Row terms.
  if (mask[isbyte ? g : (g << 2)] == 0) {
    float A = ld2(nl2p, g), Q = ld2(nt2p, g), Cc = ld2(ltp, g);
    nv = 1.f;
    mse = A + Q - 2.f * Cc;
    coss = 1.f - Cc / (fmaxf(sqrtf(A), 1e-8f) * fmaxf(sqrtf(Q), 1e-8f));
  }

  // Pair terms.
  if (g < LP) {
    const int b = g / 63;
    const int s = g - b * 63;
    const unsigned long long pbb = vb[b - B0] & (vb[b - B0] >> 1);
    if ((pbb >> s) & 1ull) {
      const int i0 = b * S_DIM + s;
      float dl = ld2(ajlp, i0) / (fmaxf(sqrtf(ld2(nl2p, i0)), 1e-6f) *
                                  fmaxf(sqrtf(ld2(nl2p, i0 + 1)), 1e-6f));
      float dt = ld2(ajtp, i0) / (fmaxf(sqrtf(ld2(nt2p, i0)), 1e-6f) *
                                  fmaxf(sqrtf(ld2(nt2p, i0 + 1)), 1e-6f));
      float wv = dl - dt;
      dsum = wv * wv;
      cntf = 1.f;

      // Next valid pair: bit scan through the LDS window.
      int bq = b, sq = -1;
      bool found = false, fellback = false;
      unsigned long long cur = pbb & (~0ull << (s + 1));
      while (true) {
        if (cur) { sq = __builtin_ctzll(cur); found = true; break; }
        ++bq;
        if (bq >= B_DIM) break;
        if (bq - B0 < 16) {
          cur = vb[bq - B0] & (vb[bq - B0] >> 1);
        } else {
          fellback = true;
          break;
        }
      }
      if (fellback) {  // correctness fallback; ~never taken for random masks
        while (bq < B_DIM && !found) {
          for (int s2 = 0; s2 < 63; ++s2) {
            int r0 = bq * S_DIM + s2;
            bool v1 = mask[isbyte ? r0 : (r0 << 2)] == 0;
            bool v2 = mask[isbyte ? (r0 + 1) : ((r0 + 1) << 2)] == 0;
            if (v1 && v2) { sq = s2; found = true; break; }
          }
          if (!found) ++bq;
        }
      }
      if (found) {
        const int j0 = bq * S_DIM + sq;
        float dlq = ld2(ajlp, j0) / (fmaxf(sqrtf(ld2(nl2p, j0)), 1e-6f) *
                                     fmaxf(sqrtf(ld2(nl2p, j0 + 1)), 1e-6f));
        float dtq = ld2(ajtp, j0) / (fmaxf(sqrtf(ld2(nt2p, j0)), 1e-6f) *
                                     fmaxf(sqrtf(ld2(nt2p, j0 + 1)), 1e-6f));
        float ddl = (dlq - dl) / ((dl != 0.f) ? dl : 1e-6f);
        float ddt = (dtq - dt) / ((dt != 0.f) ? dt : 1e-6f);
        float u = ddl - ddt;
        ddsum = u * u;
      }
    }
  }

  float vals[6] = {nv, mse, coss, dsum, ddsum, cntf};
#pragma unroll
  for (int k2 = 0; k2 < 6; ++k2) {
    float v = red64_uni(vals[k2]);
    if (lane == 0) psum[k2][w] = v;
  }
  __syncthreads();
  if (tid == 0) {
#pragma unroll
    for (int k2 = 0; k2 < 6; ++k2)
      partial[k2 * NBP + blockIdx.x] = psum[k2][0] + psum[k2][1];
  }
}

// ---------------------------------------------------------------------------
// Kernel 3: combine 128 partials into the scalar loss.
// ---------------------------------------------------------------------------
__global__ __launch_bounds__(128) void final_combine_kernel(
    const float* __restrict__ ws, float* __restrict__ out) {
  const float* partial = ws + 10 * BS;
  __shared__ float sm[6][2];
  const int tid = threadIdx.x, w = tid >> 6, lane = tid & 63;
#pragma unroll
  for (int k = 0; k < 6; ++k) {
    float v = red64_uni(partial[k * NBP + tid]);
    if (lane == 0) sm[k][w] = v;
  }
  __syncthreads();
  if (tid == 0) {
    float nv   = sm[0][0] + sm[0][1];
    float mse  = sm[1][0] + sm[1][1];
    float coss = sm[2][0] + sm[2][1];
    float dsum = sm[3][0] + sm[3][1];
    float ddsm = sm[4][0] + sm[4][1];
    float cnt  = sm[5][0] + sm[5][1];
    out[0] = mse / (nv * (float)D_DIM) + coss / nv +
             dsum / fmaxf(cnt, 1.f) + (ddsm / fmaxf(cnt - 1.f, 1.f)) * 0.01f;
  }
}

extern "C" void kernel_launch(void* const* d_in, const int* in_sizes, int n_in,
                              void* d_out, int out_size, void* d_ws, size_t ws_size,
                              hipStream_t stream) {
  const float* logits = (const float*)d_in[0];
  const float* tgt    = (const float*)d_in[1];
  const unsigned char* mask = (const unsigned char*)d_in[2];
  float* out = (float*)d_out;
  float* ws  = (float*)d_ws;

  row_stats_kernel<<<dim3(2048), dim3(512), 0, stream>>>(logits, tgt, ws);
  pair_kernel<<<dim3(NBP), dim3(128), 0, stream>>>(mask, ws);
  final_combine_kernel<<<dim3(1), dim3(128), 0, stream>>>(ws, out);
}

// Round 8
// 28.807 us; speedup vs baseline: 3.8091x; 1.2925x over previous
//
#include <hip/hip_runtime.h>

#define S_DIM 64
#define B_DIM 256
#define D_DIM 1024
#define BS (B_DIM * S_DIM)        /* 16384 */
#define LP (B_DIM * (S_DIM - 1)) /* 16128 */
#define NBP 128                   /* blocks in pair_kernel */

__device__ __forceinline__ float dot4(float4 a, float4 b) {
  return a.x * b.x + a.y * b.y + a.z * b.z + a.w * b.w;
}

// DPP row_ror add (pure VALU, no LDS) + readlane finish.
template <int CTRL>
__device__ __forceinline__ float dpp_add(float v) {
  int r = __builtin_amdgcn_update_dpp(__float_as_int(v), __float_as_int(v),
                                      CTRL, 0xF, 0xF, false);
  return v + __int_as_float(r);
}

__device__ __forceinline__ float red64_uni(float v) {
  v = dpp_add<0x128>(v);  // row_ror:8
  v = dpp_add<0x124>(v);  // row_ror:4
  v = dpp_add<0x122>(v);  // row_ror:2
  v = dpp_add<0x121>(v);  // row_ror:1
  float r = __int_as_float(__builtin_amdgcn_readlane(__float_as_int(v), 0));
  r += __int_as_float(__builtin_amdgcn_readlane(__float_as_int(v), 16));
  r += __int_as_float(__builtin_amdgcn_readlane(__float_as_int(v), 32));
  r += __int_as_float(__builtin_amdgcn_readlane(__float_as_int(v), 48));
  return r;
}

// ---------------------------------------------------------------------------
// Kernel 1: per-row reductions, D split across two waves per row (h=0,1).
// Block = 512 threads = 8 waves = 4 s-chunks x 2 halves covering 8 rows of
// one batch. MASK-GATED: a row is loaded/reduced ONLY if valid (invalid rows
// contribute to no loss term), cutting logical traffic ~2x. Boundary rows
// shared through LDS (one barrier). All mask branches are wave-uniform.
// ws layout (floats): nl2p[2BS] | nt2p[2BS] | ltp[2BS] | ajlp[2BS] | ajtp[2BS]
//                     | partial[6*NBP]
// Half-partials at [2*rowid + h]; pair_kernel sums the halves. Entries for
// invalid rows/pairs are never written NOR read.
// ---------------------------------------------------------------------------
__global__ __launch_bounds__(512) void row_stats_kernel(
    const float* __restrict__ logits, const float* __restrict__ tgt,
    const unsigned char* __restrict__ mask, float* __restrict__ ws) {
  const int tid = threadIdx.x;
  const int lane = tid & 63;
  const int wv = tid >> 6;            // wave in block, 0..7
  int bid = blockIdx.x;
  bid = (bid & 7) * 256 + (bid >> 3); // XCD swizzle, bijective (2048 % 8 == 0)
  const int b  = bid >> 3;            // batch
  const int r0 = (bid & 7) << 3;      // block row base: 0,8,...,56
  const int k  = wv >> 1;             // chunk in block, 0..3
  const int h  = wv & 1;              // d-half
  const int s0 = r0 + (k << 1);       // first row of this wave's chunk

  float* nl2p = ws;
  float* nt2p = ws + 2 * BS;
  float* ltp  = ws + 4 * BS;
  float* ajlp = ws + 6 * BS;
  float* ajtp = ws + 8 * BS;

  // Mask layout detection (byte vs int32 storage), wave-local: bytes at
  // offset %4 != 0 are nonzero only for byte layout (192 random bytes).
  uchar4 det = reinterpret_cast<const uchar4*>(mask)[lane];
  const bool isbyte = __ballot((det.y | det.z | det.w) != 0) != 0ull;
  auto mvalid = [&](int s) -> bool {
    const int idx = b * S_DIM + s;
    return mask[isbyte ? idx : (idx << 2)] == 0;
  };
  const bool v0 = mvalid(s0);
  const bool v1 = mvalid(s0 + 1);
  const bool vp = (s0 > 0) && mvalid(s0 - 1);
  const bool needP  = v0 && vp;   // pair (s0-1, s0)
  const bool needP1 = v0 && v1;   // pair (s0, s0+1)

  const int fo = h * 128 + lane;  // float4 index within row (+64 for j=1)

  // Per-wave LDS export of row s0+1: [0..127]=logits half, [128..255]=tgt half
  __shared__ float4 lds[8][256];

  float4 R[4], N[4], P[4];  // rows s0, s0+1, s0-1; [0..1]=logits, [2..3]=tgt

  auto ldrow = [&](int s, float4* dst) {
    const float4* Lp = reinterpret_cast<const float4*>(
        logits + ((size_t)s * B_DIM + b) * D_DIM);
    const float4* Tp = reinterpret_cast<const float4*>(
        tgt + ((size_t)s * B_DIM + b) * D_DIM);
    dst[0] = Lp[fo];
    dst[1] = Lp[fo + 64];
    dst[2] = Tp[fo];
    dst[3] = Tp[fo + 64];
  };

  if (v0) ldrow(s0, R);
  if (v1) ldrow(s0 + 1, N);
  if (k == 0 && needP) ldrow(s0 - 1, P);  // first chunk: prev from global

  if (v1) {  // export row s0+1 for the next chunk's pair (s0+1, s0+2)
    lds[wv][lane]       = N[0];
    lds[wv][lane + 64]  = N[1];
    lds[wv][lane + 128] = N[2];
    lds[wv][lane + 192] = N[3];
  }

  // Pre-barrier: everything not involving P.
  float a0 = 0.f, a1 = 0.f, a2 = 0.f;
  float b0 = 0.f, b1 = 0.f, b2 = 0.f, b3 = 0.f, b4 = 0.f;
  if (v0) {
    a0 = dot4(R[0], R[0]) + dot4(R[1], R[1]);
    a1 = dot4(R[2], R[2]) + dot4(R[3], R[3]);
    a2 = dot4(R[0], R[2]) + dot4(R[1], R[3]);
  }
  if (v1) {
    b0 = dot4(N[0], N[0]) + dot4(N[1], N[1]);
    b1 = dot4(N[2], N[2]) + dot4(N[3], N[3]);
    b2 = dot4(N[0], N[2]) + dot4(N[1], N[3]);
  }
  if (needP1) {
    b3 = dot4(N[0], R[0]) + dot4(N[1], R[1]);  // aj[s0] logits
    b4 = dot4(N[2], R[2]) + dot4(N[3], R[3]);  // aj[s0] tgt
  }

  __syncthreads();

  float a3 = 0.f, a4 = 0.f;
  if (needP) {
    if (k != 0) {  // prev row from the previous chunk's LDS export
      P[0] = lds[wv - 2][lane];
      P[1] = lds[wv - 2][lane + 64];
      P[2] = lds[wv - 2][lane + 128];
      P[3] = lds[wv - 2][lane + 192];
    }
    a3 = dot4(R[0], P[0]) + dot4(R[1], P[1]);  // aj[s0-1] logits
    a4 = dot4(R[2], P[2]) + dot4(R[3], P[3]);  // aj[s0-1] tgt
  }

  if (v0) { a0 = red64_uni(a0); a1 = red64_uni(a1); a2 = red64_uni(a2); }
  if (needP) { a3 = red64_uni(a3); a4 = red64_uni(a4); }
  if (v1) { b0 = red64_uni(b0); b1 = red64_uni(b1); b2 = red64_uni(b2); }
  if (needP1) { b3 = red64_uni(b3); b4 = red64_uni(b4); }

  if (lane == 0) {
    const int i = b * S_DIM + s0;
    if (v0) { nl2p[2 * i + h] = a0; nt2p[2 * i + h] = a1; ltp[2 * i + h] = a2; }
    if (needP) { ajlp[2 * (i - 1) + h] = a3; ajtp[2 * (i - 1) + h] = a4; }
    if (v1) {
      const int i2 = i + 1;
      nl2p[2 * i2 + h] = b0; nt2p[2 * i2 + h] = b1; ltp[2 * i2 + h] = b2;
    }
    if (needP1) { ajlp[2 * i + h] = b3; ajtp[2 * i + h] = b4; }
  }
}

// Sum the two d-half partials with one float2 load.
__device__ __forceinline__ float ld2(const float* p, int i) {
  float2 v = reinterpret_cast<const float2*>(p)[i];
  return v.x + v.y;
}

// ---------------------------------------------------------------------------
// Kernel 2: mask-weighted row sums + pair delta/dd terms. 128 blocks x 128
// threads; ballot-built validity bitmaps make the next-valid-pair search a
// bit scan. Reads only stats entries whose validity gate passed (which
// row_stats wrote) -- never the unwritten (poisoned) ones.
// ---------------------------------------------------------------------------
__global__ __launch_bounds__(128) void pair_kernel(
    const unsigned char* __restrict__ mask, float* __restrict__ ws) {
  const float* nl2p = ws;
  const float* nt2p = ws + 2 * BS;
  const float* ltp  = ws + 4 * BS;
  const float* ajlp = ws + 6 * BS;
  const float* ajtp = ws + 8 * BS;
  float* partial = ws + 10 * BS;

  __shared__ unsigned long long vb[16];
  __shared__ float psum[6][2];
  __shared__ int s_flag;

  const int tid = threadIdx.x;
  const int w = tid >> 6, lane = tid & 63;

  if (tid == 0) s_flag = 0;
  __syncthreads();
  int any = 0;
  for (int i = tid; i < 1024; i += 128)
    if ((i & 3) == 1 && mask[i]) any = 1;
  if (any) s_flag = 1;
  __syncthreads();
  const bool isbyte = (s_flag != 0);

  int B0 = (blockIdx.x * 128) / 63;
  if (B0 > B_DIM - 16) B0 = B_DIM - 16;

#pragma unroll
  for (int k = 0; k < 8; ++k) {
    const int q = k * 2 + w;
    const int g2 = (B0 + q) * 64 + lane;
    bool val = mask[isbyte ? g2 : (g2 << 2)] == 0;
    unsigned long long bal = __ballot(val);
    if (lane == 0) vb[q] = bal;
  }
  __syncthreads();

  const int g = blockIdx.x * 128 + tid;  // row id and pair id

  float nv = 0.f, mse = 0.f, coss = 0.f, dsum = 0.f, ddsum = 0.f, cntf = 0.f;

  // Row terms.
  if (mask[isbyte ? g : (g << 2)] == 0) {
    float A = ld2(nl2p, g), Q = ld2(nt2p, g), Cc = ld2(ltp, g);
    nv = 1.f;
    mse = A + Q - 2.f * Cc;
    coss = 1.f - Cc / (fmaxf(sqrtf(A), 1e-8f) * fmaxf(sqrtf(Q), 1e-8f));
  }

  // Pair terms.
  if (g < LP) {
    const int b = g / 63;
    const int s = g - b * 63;
    const unsigned long long pbb = vb[b - B0] & (vb[b - B0] >> 1);
    if ((pbb >> s) & 1ull) {
      const int i0 = b * S_DIM + s;
      float dl = ld2(ajlp, i0) / (fmaxf(sqrtf(ld2(nl2p, i0)), 1e-6f) *
                                  fmaxf(sqrtf(ld2(nl2p, i0 + 1)), 1e-6f));
      float dt = ld2(ajtp, i0) / (fmaxf(sqrtf(ld2(nt2p, i0)), 1e-6f) *
                                  fmaxf(sqrtf(ld2(nt2p, i0 + 1)), 1e-6f));
      float wv = dl - dt;
      dsum = wv * wv;
      cntf = 1.f;

      // Next valid pair: bit scan through the LDS window.
      int bq = b, sq = -1;
      bool found = false, fellback = false;
      unsigned long long cur = pbb & (~0ull << (s + 1));
      while (true) {
        if (cur) { sq = __builtin_ctzll(cur); found = true; break; }
        ++bq;
        if (bq >= B_DIM) break;
        if (bq - B0 < 16) {
          cur = vb[bq - B0] & (vb[bq - B0] >> 1);
        } else {
          fellback = true;
          break;
        }
      }
      if (fellback) {  // correctness fallback; ~never taken for random masks
        while (bq < B_DIM && !found) {
          for (int s2 = 0; s2 < 63; ++s2) {
            int r0 = bq * S_DIM + s2;
            bool v1 = mask[isbyte ? r0 : (r0 << 2)] == 0;
            bool v2 = mask[isbyte ? (r0 + 1) : ((r0 + 1) << 2)] == 0;
            if (v1 && v2) { sq = s2; found = true; break; }
          }
          if (!found) ++bq;
        }
      }
      if (found) {
        const int j0 = bq * S_DIM + sq;
        float dlq = ld2(ajlp, j0) / (fmaxf(sqrtf(ld2(nl2p, j0)), 1e-6f) *
                                     fmaxf(sqrtf(ld2(nl2p, j0 + 1)), 1e-6f));
        float dtq = ld2(ajtp, j0) / (fmaxf(sqrtf(ld2(nt2p, j0)), 1e-6f) *
                                     fmaxf(sqrtf(ld2(nt2p, j0 + 1)), 1e-6f));
        float ddl = (dlq - dl) / ((dl != 0.f) ? dl : 1e-6f);
        float ddt = (dtq - dt) / ((dt != 0.f) ? dt : 1e-6f);
        float u = ddl - ddt;
        ddsum = u * u;
      }
    }
  }

  float vals[6] = {nv, mse, coss, dsum, ddsum, cntf};
#pragma unroll
  for (int k2 = 0; k2 < 6; ++k2) {
    float v = red64_uni(vals[k2]);
    if (lane == 0) psum[k2][w] = v;
  }
  __syncthreads();
  if (tid == 0) {
#pragma unroll
    for (int k2 = 0; k2 < 6; ++k2)
      partial[k2 * NBP + blockIdx.x] = psum[k2][0] + psum[k2][1];
  }
}

// ---------------------------------------------------------------------------
// Kernel 3: combine 128 partials into the scalar loss.
// ---------------------------------------------------------------------------
__global__ __launch_bounds__(128) void final_combine_kernel(
    const float* __restrict__ ws, float* __restrict__ out) {
  const float* partial = ws + 10 * BS;
  __shared__ float sm[6][2];
  const int tid = threadIdx.x, w = tid >> 6, lane = tid & 63;
#pragma unroll
  for (int k = 0; k < 6; ++k) {
    float v = red64_uni(partial[k * NBP + tid]);
    if (lane == 0) sm[k][w] = v;
  }
  __syncthreads();
  if (tid == 0) {
    float nv   = sm[0][0] + sm[0][1];
    float mse  = sm[1][0] + sm[1][1];
    float coss = sm[2][0] + sm[2][1];
    float dsum = sm[3][0] + sm[3][1];
    float ddsm = sm[4][0] + sm[4][1];
    float cnt  = sm[5][0] + sm[5][1];
    out[0] = mse / (nv * (float)D_DIM) + coss / nv +
             dsum / fmaxf(cnt, 1.f) + (ddsm / fmaxf(cnt - 1.f, 1.f)) * 0.01f;
  }
}

extern "C" void kernel_launch(void* const* d_in, const int* in_sizes, int n_in,
                              void* d_out, int out_size, void* d_ws, size_t ws_size,
                              hipStream_t stream) {
  const float* logits = (const float*)d_in[0];
  const float* tgt    = (const float*)d_in[1];
  const unsigned char* mask = (const unsigned char*)d_in[2];
  float* out = (float*)d_out;
  float* ws  = (float*)d_ws;

  row_stats_kernel<<<dim3(2048), dim3(512), 0, stream>>>(logits, tgt, mask, ws);
  pair_kernel<<<dim3(NBP), dim3(128), 0, stream>>>(mask, ws);
  final_combine_kernel<<<dim3(1), dim3(128), 0, stream>>>(ws, out);
}